// Round 14
// baseline (142.718 us; speedup 1.0000x reference)
//
#include <hip/hip_runtime.h>
#include <hip/hip_bf16.h>
#include <cstdint>

// Problem constants: B=1, C=256, F=8, H=32, W=32 -> N = 8192 spatial.
#define NSP 8192
#define CCH 256
#define KBLK 32
#define NSPLIT 8
#define KEYS_PER_SPLIT 1024
#define NTILES 32  // KEYS_PER_SPLIT / KBLK

typedef __attribute__((ext_vector_type(4))) float f32x4;
typedef __attribute__((ext_vector_type(16))) float f32x16;
typedef __attribute__((ext_vector_type(8))) short bf16x8;
typedef __attribute__((ext_vector_type(2))) unsigned int u32x2;

__device__ __forceinline__ ushort f2bf(float f) {
  union { float f; uint32_t u; } v; v.f = f;
  uint32_t r = (v.u + 0x7FFFu + ((v.u >> 16) & 1u)) >> 16;
  return (ushort)r;
}
__device__ __forceinline__ float bf2f(ushort u) {
  union { uint32_t u; float f; } v; v.u = ((uint32_t)u) << 16; return v.f;
}
__device__ __forceinline__ uint32_t pk2bf(float lo, float hi) {
  __hip_bfloat162 h = __float22bfloat162_rn({lo, hi});
  union { __hip_bfloat162 h; uint32_t u; } c; c.h = h; return c.u;
}

// global -> LDS direct copy, 16B per lane. LDS dest must be wave-uniform base.
__device__ __forceinline__ void gload_lds16(const void* g, void* l) {
  auto gp = (const __attribute__((address_space(1))) uint32_t*)(uintptr_t)g;
  auto lp = (__attribute__((address_space(3))) uint32_t*)(uint32_t)(uintptr_t)l;
  __builtin_amdgcn_global_load_lds(gp, lp, 16, 0, 0);
}

// exchange: swaps hi 32 lanes of a with lo 32 lanes of b
__device__ __forceinline__ void perm32swap(uint32_t& a, uint32_t& b) {
#if __has_builtin(__builtin_amdgcn_permlane32_swap)
  u32x2 r = __builtin_amdgcn_permlane32_swap(a, b, false, false);
  a = r[0]; b = r[1];
#else
  uint32_t sa = __shfl_xor((int)a, 32), sb = __shfl_xor((int)b, 32);
  bool lo = (threadIdx.x & 63) < 32;
  uint32_t na = lo ? a : sb;
  uint32_t nb = lo ? sa : b;
  a = na; b = nb;
#endif
}

// ---------------- K1: per-block partial sum/sumsq over x (2M floats) --------
__global__ __launch_bounds__(256) void k_stats1(const float* __restrict__ x,
                                                float* __restrict__ part) {
  int t = threadIdx.x, b = blockIdx.x;
  float s = 0.f, ss = 0.f;
  const float4* x4 = (const float4*)x;
  for (int i = 0; i < 4; ++i) {
    float4 v = x4[(size_t)i * 131072 + b * 256 + t];
    s += v.x + v.y + v.z + v.w;
    ss += v.x * v.x + v.y * v.y + v.z * v.z + v.w * v.w;
  }
  for (int m = 1; m < 64; m <<= 1) { s += __shfl_xor(s, m); ss += __shfl_xor(ss, m); }
  __shared__ float ls[4], lss[4];
  int w = t >> 6, lane = t & 63;
  if (lane == 0) { ls[w] = s; lss[w] = ss; }
  __syncthreads();
  if (t == 0) {
    part[b * 2 + 0] = ls[0] + ls[1] + ls[2] + ls[3];
    part[b * 2 + 1] = lss[0] + lss[1] + lss[2] + lss[3];
  }
}

// ---------------- K2: cast weights to bf16; block 1024 finalizes stats ------
__global__ __launch_bounds__(256) void k_castw(const float* __restrict__ qw, const float* __restrict__ kw,
                                               const float* __restrict__ vw, const float* __restrict__ ow,
                                               ushort* __restrict__ wqkv, ushort* __restrict__ wo,
                                               const float* __restrict__ part, float* __restrict__ stat) {
  if (blockIdx.x == 1024) {  // stats finalize
    int t = threadIdx.x;
    float s = 0.f, ss = 0.f;
    for (int i = t; i < 512; i += 256) { s += part[i * 2]; ss += part[i * 2 + 1]; }
    for (int m = 1; m < 64; m <<= 1) { s += __shfl_xor(s, m); ss += __shfl_xor(ss, m); }
    __shared__ float ls[4], lss[4];
    int w = t >> 6, lane = t & 63;
    if (lane == 0) { ls[w] = s; lss[w] = ss; }
    __syncthreads();
    if (t == 0) {
      float sum = ls[0] + ls[1] + ls[2] + ls[3];
      float ssum = lss[0] + lss[1] + lss[2] + lss[3];
      float mean = sum * (1.f / 2097152.f);
      float var = ssum * (1.f / 2097152.f) - mean * mean;
      stat[0] = mean;
      stat[1] = rsqrtf(var + 1e-5f);
    }
    return;
  }
  int idx = blockIdx.x * 256 + threadIdx.x;  // 262144 total
  if (idx < 65536) wqkv[idx] = f2bf(qw[idx]);
  else if (idx < 131072) wqkv[idx] = f2bf(kw[idx - 65536]);
  else if (idx < 196608) wqkv[idx] = f2bf(vw[idx - 131072]);
  else wo[idx - 196608] = f2bf(ow[idx - 196608]);
}

// ---------------- K3: normalize + transpose -> xnT bf16 [8192][256] ---------
__global__ __launch_bounds__(256) void k_norm_t(const float* __restrict__ x,
                                                const float* __restrict__ gw, const float* __restrict__ gb,
                                                const float* __restrict__ stat, ushort* __restrict__ xnT) {
  __shared__ float tile[64][66];
  int n0 = blockIdx.x * 64, c0 = blockIdx.y * 64;
  int t = threadIdx.x, colr = t & 63, rq = t >> 6;
  float mean = stat[0], rinv = stat[1];
  for (int rr = 0; rr < 16; ++rr) {
    int row = rr * 4 + rq;  // c-local
    int c = c0 + row;
    float v = x[(size_t)c * NSP + n0 + colr];
    tile[row][colr] = (v - mean) * rinv * gw[c] + gb[c];
  }
  __syncthreads();
  for (int rr = 0; rr < 16; ++rr) {
    int rowW = rr * 4 + rq;  // n-local
    xnT[(size_t)(n0 + rowW) * 256 + c0 + colr] = f2bf(tile[colr][rowW]);
  }
}

// ---------------- K4: QKV GEMM -> qT [8192][256],
//   K packed per key-tile: k_tiles[256 tile][32 s][32 key][8]  (s = chan/8)
//   V packed per key-tile: v_tiles[256 tile][4 slot][256 c][8 m]
__global__ __launch_bounds__(256) void k_qkv(const ushort* __restrict__ xnT, const ushort* __restrict__ wqkv,
                                             const float* __restrict__ qb, const float* __restrict__ kb,
                                             const float* __restrict__ vb,
                                             ushort* __restrict__ qT, ushort* __restrict__ k_tiles,
                                             ushort* __restrict__ v_tiles) {
  __shared__ ushort tile[64][80];  // transpose bounce (160B rows, 16B aligned)
  int nb = blockIdx.x, ob = blockIdx.y;
  int w = threadIdx.x >> 6, lane = threadIdx.x & 63;
  int l16 = lane & 15, kgrp = lane >> 4;
  int n_row = nb * 64 + w * 16 + l16;
  bf16x8 a[8];
  const bf16x8* arow = (const bf16x8*)(xnT + (size_t)n_row * 256);
  for (int ks = 0; ks < 8; ++ks) a[ks] = arow[ks * 4 + kgrp];
  f32x4 acc[4];
  for (int ct = 0; ct < 4; ++ct) {
    int o = ob * 64 + ct * 16 + l16;
    const bf16x8* brow = (const bf16x8*)(wqkv + (size_t)o * 256);
    f32x4 c = {0.f, 0.f, 0.f, 0.f};
    for (int ks = 0; ks < 8; ++ks)
      c = __builtin_amdgcn_mfma_f32_16x16x32_bf16(a[ks], brow[ks * 4 + kgrp], c, 0, 0, 0);
    acc[ct] = c;
  }
  const float SCALE = 0.0625f * 1.44269504088896340736f;  // (1/sqrt(C)) * log2(e)
  if (ob < 4) {  // q outputs: direct scattered write
    for (int ct = 0; ct < 4; ++ct) {
      int o = ob * 64 + ct * 16 + l16;
      for (int r = 0; r < 4; ++r) {
        int n = nb * 64 + w * 16 + kgrp * 4 + r;
        qT[(size_t)n * 256 + o] = f2bf((acc[ct][r] + qb[o]) * SCALE);
      }
    }
  } else if (ob < 8) {  // k outputs: bounce [n][c], emit tile-packed transposed
    for (int ct = 0; ct < 4; ++ct) {
      int o_l = ct * 16 + l16;  // channel-local 0..63
      for (int r = 0; r < 4; ++r) {
        int n_l = w * 16 + kgrp * 4 + r;  // key-local 0..63
        tile[n_l][o_l] = f2bf(acc[ct][r] + kb[(ob - 4) * 64 + o_l]);
      }
    }
    __syncthreads();
    // k_tiles element (tile, s, key, j) = K[key][c = s*8+j]
    for (int j = 0; j < 2; ++j) {
      int idx = j * 256 + threadIdx.x;          // 512 granules of 16B
      int tile_l = idx >> 8, s = (idx >> 5) & 7, key = idx & 31;
      size_t off = (size_t)(nb * 2 + tile_l) * 16384 +
                   (size_t)((ob - 4) * 8 + s) * 512 + key * 16;
      *(uint4*)((char*)k_tiles + off) = *(const uint4*)&tile[tile_l * 32 + key][s * 8];
    }
  } else {  // v outputs: bounce [c][n], emit tile-packed layout, coalesced
    for (int ct = 0; ct < 4; ++ct) {
      int o_l = ct * 16 + l16;
      for (int r = 0; r < 4; ++r) {
        int n_l = w * 16 + kgrp * 4 + r;
        tile[o_l][n_l] = f2bf(acc[ct][r] + vb[(ob - 8) * 64 + o_l]);
      }
    }
    __syncthreads();
    // v_tiles element (t, s, c, m) at ushort offset t*8192 + s*2048 + c*8 + m
    for (int j = 0; j < 2; ++j) {
      int idx = j * 256 + threadIdx.x;          // 512 stores of 16B
      int tile_l = idx >> 8, slot = (idx >> 6) & 3, c_l = idx & 63;
      size_t off = (size_t)(nb * 2 + tile_l) * 8192 + slot * 2048 +
                   (size_t)((ob - 8) * 64 + c_l) * 8;
      *(uint4*)((char*)v_tiles + off * 2) = *(const uint4*)&tile[c_l][tile_l * 32 + slot * 8];
    }
  }
}

// ---------------- K5: flash attention, phase-split pipeline -----------------
// grid 256 = 1 block/CU (32 qblk x 8 splits, split = bid&7 -> XCD-exact).
// 512 threads (8 waves), wave owns 32 q. LDS 64KB: K dbuf + V dbuf (linear).
// Iter tt: phase A = QK(tt) 16 MFMA interleaved 2:1 with PV-half1(tt-1);
// phase B = PV-half2(tt-1) MFMAs overlapped with SPECULATIVE softmax(tt)
// (exp with old m_r -- valid in defer-max fast path; rare slow path fixes up
// by scaling P/sums/acc/l_p by alpha). m_r init 0 keeps speculation finite.
// Register-neutral vs r13: no second S register block needed.
__global__ __launch_bounds__(512, 2) void k_attn(const ushort* __restrict__ qT, const ushort* __restrict__ k_tiles,
                                                 const ushort* __restrict__ v_tiles,
                                                 ushort* __restrict__ Opart, float* __restrict__ mpart,
                                                 float* __restrict__ lpart) {
  __shared__ __align__(16) ushort SMEM[32768];  // 64 KB
  ushort* k_lds = SMEM;          // 2 x 8192: [32 s][32 key][8] (linear tile image)
  ushort* v_lds = SMEM + 16384;  // 2 x 8192: [4 slot][256 c][8 m] (linear tile image)

  int bid = blockIdx.x;
  int split = bid & 7, qblk = bid >> 3;
  int t = threadIdx.x, w = t >> 6, lane = t & 63;
  int l31 = lane & 31, lhi = lane >> 5;
  int q0w = qblk * 256 + w * 32;

  // Q as B-operand fragments: lane holds q=l31, channels cs*16 + lhi*8 + j
  bf16x8 qf[16];
  {
    const char* qbase = (const char*)qT + (size_t)(q0w + l31) * 512;
#pragma unroll
    for (int cs = 0; cs < 16; ++cs)
      qf[cs] = *(const bf16x8*)(qbase + cs * 32 + lhi * 16);
  }

  f32x16 acc[8] = {};                 // O[c][q]: 8 blocks of 32 channels (AGPRs)
  float m_r = 0.f, l_p = 0.f;         // m_r starts 0 (scores ~N(0,1.5)) for finite speculation
  bf16x8 pf0, pf1;                    // P fragments of the previous tile

  const char* kT_b = (const char*)k_tiles + (size_t)split * KEYS_PER_SPLIT * 512;
  const char* v_b = (const char*)v_tiles + (size_t)split * KEYS_PER_SPLIT * 512;

  auto STAGE_K = [&](int tt) {
    const char* ksrc = kT_b + (size_t)tt * 16384 + w * 2048;
    char* kdst = (char*)(k_lds + (tt & 1) * 8192) + w * 2048;
#pragma unroll
    for (int i = 0; i < 2; ++i)
      gload_lds16(ksrc + i * 1024 + lane * 16, kdst + i * 1024);
  };
  auto STAGE_V = [&](int tt) {
    char* vdst = (char*)(v_lds + (tt & 1) * 8192) + w * 2048;
    const char* vsrc = v_b + (size_t)tt * 16384 + w * 2048;
#pragma unroll
    for (int i = 0; i < 2; ++i)
      gload_lds16(vsrc + i * 1024 + lane * 16, vdst + i * 1024);
  };

  // pack S0 (post-exp) -> pf0, pf1
  auto PACK = [&](const f32x16& S0) {
    union { uint32_t w[4]; bf16x8 v; } u;
    {
      uint32_t x = pk2bf(S0[0], S0[1]), y = pk2bf(S0[4], S0[5]);
      perm32swap(x, y);
      uint32_t x2_ = pk2bf(S0[2], S0[3]), y2 = pk2bf(S0[6], S0[7]);
      perm32swap(x2_, y2);
      u.w[0] = x; u.w[1] = x2_; u.w[2] = y; u.w[3] = y2;
      pf0 = u.v;
    }
    {
      uint32_t x = pk2bf(S0[8], S0[9]), y = pk2bf(S0[12], S0[13]);
      perm32swap(x, y);
      uint32_t x2_ = pk2bf(S0[10], S0[11]), y2 = pk2bf(S0[14], S0[15]);
      perm32swap(x2_, y2);
      u.w[0] = x; u.w[1] = x2_; u.w[2] = y; u.w[3] = y2;
      pf1 = u.v;
    }
  };

  STAGE_K(0);  // prologue

  // ---- iter 0 (peeled): QK(0) + serial softmax(0) ----
  asm volatile("s_waitcnt vmcnt(0) lgkmcnt(0)" ::: "memory");
  __builtin_amdgcn_s_barrier();
  __builtin_amdgcn_sched_barrier(0);
  STAGE_K(1);
  STAGE_V(0);
  {
    const ushort* kl = k_lds;  // buf 0
    f32x16 S0 = {};
    __builtin_amdgcn_s_setprio(1);
#pragma unroll
    for (int cs = 0; cs < 16; ++cs) {
      int slot = cs * 2 + lhi;
      bf16x8 a0 = *(const bf16x8*)(kl + slot * 256 + l31 * 8);
      S0 = __builtin_amdgcn_mfma_f32_32x32x16_bf16(a0, qf[cs], S0, 0, 0, 0);
    }
    __builtin_amdgcn_s_setprio(0);
    float x0 = fmaxf(S0[0], S0[1]), x1 = fmaxf(S0[2], S0[3]);
    float x2 = fmaxf(S0[4], S0[5]), x3 = fmaxf(S0[6], S0[7]);
    float x4 = fmaxf(S0[8], S0[9]), x5 = fmaxf(S0[10], S0[11]);
    float x6 = fmaxf(S0[12], S0[13]), x7 = fmaxf(S0[14], S0[15]);
    float pm = fmaxf(fmaxf(fmaxf(x0, x1), fmaxf(x2, x3)),
                     fmaxf(fmaxf(x4, x5), fmaxf(x6, x7)));
    pm = fmaxf(pm, __shfl_xor(pm, 32));
    if (!__all(pm <= m_r + 8.f)) m_r = fmaxf(m_r, pm);  // acc=0, l_p=0: no alpha
    float t0s = 0.f, t1s = 0.f;
#pragma unroll
    for (int r = 0; r < 16; ++r) {
      S0[r] = __builtin_amdgcn_exp2f(S0[r] - m_r);
      if (r & 1) t1s += S0[r]; else t0s += S0[r];
    }
    l_p = t0s + t1s;
    PACK(S0);
  }

#pragma unroll 1
  for (int tt = 1; tt < NTILES; ++tt) {
    asm volatile("s_waitcnt vmcnt(0) lgkmcnt(0)" ::: "memory");
    __builtin_amdgcn_s_barrier();
    __builtin_amdgcn_sched_barrier(0);
    if (tt + 1 < NTILES) STAGE_K(tt + 1);
    STAGE_V(tt);

    const ushort* kl = k_lds + (tt & 1) * 8192;
    const ushort* vl = v_lds + ((tt - 1) & 1) * 8192;
    f32x16 S0 = {};
    __builtin_amdgcn_s_setprio(1);
    // ---- phase A: QK(tt) 2:1 with PV-half1(tt-1) ----
#pragma unroll
    for (int cb = 0; cb < 8; ++cb) {
      bf16x8 va0 = *(const bf16x8*)(vl + lhi * 2048 + (cb * 32 + l31) * 8);
      acc[cb] = __builtin_amdgcn_mfma_f32_32x32x16_bf16(va0, pf0, acc[cb], 0, 0, 0);
      {
        bf16x8 ka = *(const bf16x8*)(kl + (4 * cb + lhi) * 256 + l31 * 8);
        S0 = __builtin_amdgcn_mfma_f32_32x32x16_bf16(ka, qf[2 * cb], S0, 0, 0, 0);
      }
      {
        bf16x8 ka = *(const bf16x8*)(kl + (4 * cb + 2 + lhi) * 256 + l31 * 8);
        S0 = __builtin_amdgcn_mfma_f32_32x32x16_bf16(ka, qf[2 * cb + 1], S0, 0, 0, 0);
      }
    }
    // ---- phase B: PV-half2(tt-1) || speculative softmax(tt) ----
    float pm0 = -1e30f, pm1 = -1e30f;
    float t0s = 0.f, t1s = 0.f;
#pragma unroll
    for (int cb = 0; cb < 8; ++cb) {
      bf16x8 va1 = *(const bf16x8*)(vl + (2 + lhi) * 2048 + (cb * 32 + l31) * 8);
      acc[cb] = __builtin_amdgcn_mfma_f32_32x32x16_bf16(va1, pf1, acc[cb], 0, 0, 0);
      pm0 = fmaxf(pm0, S0[2 * cb]);
      S0[2 * cb] = __builtin_amdgcn_exp2f(S0[2 * cb] - m_r);
      t0s += S0[2 * cb];
      pm1 = fmaxf(pm1, S0[2 * cb + 1]);
      S0[2 * cb + 1] = __builtin_amdgcn_exp2f(S0[2 * cb + 1] - m_r);
      t1s += S0[2 * cb + 1];
    }
    __builtin_amdgcn_s_setprio(0);
    // ---- tail: max check + rare fixup + pack ----
    float pm = fmaxf(pm0, pm1);
    pm = fmaxf(pm, __shfl_xor(pm, 32));
    if (!__all(pm <= m_r + 8.f)) {   // slow path (rare): re-scale speculation
      float mn = fmaxf(m_r, pm);
      float alpha = __builtin_amdgcn_exp2f(m_r - mn);
      m_r = mn;
      l_p *= alpha; t0s *= alpha; t1s *= alpha;
#pragma unroll
      for (int r = 0; r < 16; ++r) S0[r] *= alpha;
#pragma unroll
      for (int cb = 0; cb < 8; ++cb)
#pragma unroll
        for (int r = 0; r < 16; ++r) acc[cb][r] *= alpha;
    }
    l_p += t0s + t1s;
    PACK(S0);
  }

  // ---- drain pipeline: PV(NTILES-1), both halves ----
  asm volatile("s_waitcnt vmcnt(0) lgkmcnt(0)" ::: "memory");
  __builtin_amdgcn_s_barrier();
  {
    const ushort* vl = v_lds + ((NTILES - 1) & 1) * 8192;
    __builtin_amdgcn_s_setprio(1);
#pragma unroll
    for (int cb = 0; cb < 8; ++cb) {
      bf16x8 va0 = *(const bf16x8*)(vl + lhi * 2048 + (cb * 32 + l31) * 8);
      acc[cb] = __builtin_amdgcn_mfma_f32_32x32x16_bf16(va0, pf0, acc[cb], 0, 0, 0);
      bf16x8 va1 = *(const bf16x8*)(vl + (2 + lhi) * 2048 + (cb * 32 + l31) * 8);
      acc[cb] = __builtin_amdgcn_mfma_f32_32x32x16_bf16(va1, pf1, acc[cb], 0, 0, 0);
    }
    __builtin_amdgcn_s_setprio(0);
  }

  // all waves done with LDS before reusing it as epilogue scratch
  asm volatile("s_waitcnt lgkmcnt(0)" ::: "memory");
  __builtin_amdgcn_s_barrier();

  // ---- epilogue: l reduce, O -> LDS transpose (64-c chunks) -> coalesced ----
  float l_tot = l_p + __shfl_xor(l_p, 32);

  // per-wave scratch: 32 q-rows x 144B (64 c x 2B + 16B pad); 8 waves = 36KB
  char* eb = (char*)SMEM + w * 4608;
  size_t gq0 = (size_t)split * NSP + q0w;
#pragma unroll
  for (int ch = 0; ch < 4; ++ch) {
#pragma unroll
    for (int cb2 = 0; cb2 < 2; ++cb2) {
      int cb = ch * 2 + cb2;
#pragma unroll
      for (int g = 0; g < 4; ++g) {
        int cl = cb2 * 32 + g * 8 + 4 * lhi;
        *(uint32_t*)(eb + l31 * 144 + cl * 2) = pk2bf(acc[cb][g * 4 + 0], acc[cb][g * 4 + 1]);
        *(uint32_t*)(eb + l31 * 144 + cl * 2 + 4) = pk2bf(acc[cb][g * 4 + 2], acc[cb][g * 4 + 3]);
      }
    }
    asm volatile("s_waitcnt lgkmcnt(0)" ::: "memory");
    __builtin_amdgcn_sched_barrier(0);
#pragma unroll
    for (int i = 0; i < 4; ++i) {
      int flat = i * 1024 + lane * 16;
      int qr = flat >> 7, off = flat & 127;
      uint4 val = *(const uint4*)(eb + qr * 144 + off);
      *(uint4*)((char*)Opart + (gq0 + qr) * 512 + ch * 128 + off) = val;
    }
    asm volatile("s_waitcnt lgkmcnt(0)" ::: "memory");
    __builtin_amdgcn_sched_barrier(0);
  }
  if (lane < 32) {
    int q = q0w + l31;
    mpart[split * NSP + q] = m_r;
    lpart[split * NSP + q] = l_tot;
  }
}

// ---------------- K6: fused combine + out-projection + residual -------------
// grid 128 (nb, 64 n-rows each) x 512 threads (8 waves).
// Phase 1: combine 8 split partials -> attL LDS tile [c8][n][8] (v_tiles style).
// Phase 2: out[o][n] = xn + wo @ att + ob via 32x32x16 MFMA (wave w: o=w*32..+32).
__global__ __launch_bounds__(512) void k_finalc(const ushort* __restrict__ Opart,
                                                const float* __restrict__ mpart,
                                                const float* __restrict__ lpart,
                                                const ushort* __restrict__ wo,
                                                const float* __restrict__ ob,
                                                const float* __restrict__ x,
                                                const float* __restrict__ gw, const float* __restrict__ gb,
                                                const float* __restrict__ stat,
                                                float* __restrict__ out) {
  __shared__ __align__(16) ushort attL[32][64][8];  // [c8][n][8c] = 32KB
  __shared__ float wtab[8][64];                     // normalized split weights
  int nb = blockIdx.x;
  int t = threadIdx.x, w = t >> 6, lane = t & 63;
  int l31 = lane & 31, lhi = lane >> 5;
  float mean = stat[0], rinv = stat[1];

  if (t < 64) {
    int n = nb * 64 + t;
    float mv[8], M = -1e30f;
#pragma unroll
    for (int s = 0; s < 8; ++s) { mv[s] = mpart[s * NSP + n]; M = fmaxf(M, mv[s]); }
    float L = 0.f, wv[8];
#pragma unroll
    for (int s = 0; s < 8; ++s) {
      wv[s] = __builtin_amdgcn_exp2f(mv[s] - M);
      L += wv[s] * lpart[s * NSP + n];
    }
    float rL = 1.f / L;
#pragma unroll
    for (int s = 0; s < 8; ++s) wtab[s][t] = wv[s] * rL;
  }
  __syncthreads();
  // combine: 4 granules of 8 channels per thread
#pragma unroll
  for (int i = 0; i < 4; ++i) {
    int flat = i * 512 + t;
    int n = flat >> 5, c8 = flat & 31;
    float av[8] = {};
#pragma unroll
    for (int s = 0; s < 8; ++s) {
      float wn = wtab[s][n];
      bf16x8 o8 = *(const bf16x8*)(Opart + ((size_t)s * NSP + nb * 64 + n) * 256 + c8 * 8);
#pragma unroll
      for (int j = 0; j < 8; ++j) av[j] += wn * bf2f((ushort)o8[j]);
    }
    uint4 pk;
    pk.x = pk2bf(av[0], av[1]); pk.y = pk2bf(av[2], av[3]);
    pk.z = pk2bf(av[4], av[5]); pk.w = pk2bf(av[6], av[7]);
    *(uint4*)&attL[c8][n][0] = pk;
  }
  __syncthreads();
  // GEMM: wave w handles o in [w*32, w*32+32), both 32-n halves
  int obase = w * 32;
#pragma unroll
  for (int half = 0; half < 2; ++half) {
    f32x16 c = {};
#pragma unroll
    for (int cs = 0; cs < 16; ++cs) {
      bf16x8 a = *(const bf16x8*)(wo + (size_t)(obase + l31) * 256 + cs * 16 + lhi * 8);
      bf16x8 b = *(const bf16x8*)&attL[cs * 2 + lhi][half * 32 + l31][0];
      c = __builtin_amdgcn_mfma_f32_32x32x16_bf16(a, b, c, 0, 0, 0);
    }
#pragma unroll
    for (int r = 0; r < 16; ++r) {
      int o = obase + (r & 3) + 8 * (r >> 2) + 4 * lhi;
      int n = nb * 64 + half * 32 + l31;
      float xv = x[(size_t)o * NSP + n];
      float xn = (xv - mean) * rinv * gw[o] + gb[o];
      out[(size_t)o * NSP + n] = xn + c[r] + ob[o];
    }
  }
}

extern "C" void kernel_launch(void* const* d_in, const int* in_sizes, int n_in,
                              void* d_out, int out_size, void* d_ws, size_t ws_size,
                              hipStream_t stream) {
  const float* x = (const float*)d_in[0];
  const float* gw = (const float*)d_in[1];
  const float* gb = (const float*)d_in[2];
  const float* qw = (const float*)d_in[3];
  const float* qbv = (const float*)d_in[4];
  const float* kw = (const float*)d_in[5];
  const float* kbv = (const float*)d_in[6];
  const float* vw = (const float*)d_in[7];
  const float* vbv = (const float*)d_in[8];
  const float* ow = (const float*)d_in[9];
  const float* obv = (const float*)d_in[10];
  float* out = (float*)d_out;
  char* ws = (char*)d_ws;
  const size_t KB = 1024, MB = 1048576;
  // region plan (high-water 49 MB):
  //  0..4K      part
  //  60K        stat
  //  64..448K   wqkv (dead after k_qkv) -> mpart (256K) overlays
  //  448..576K  wo (live until k_finalc)
  //  576..832K  lpart
  //  1..5MB     xnT (k_norm_t->k_qkv)
  //  5..9MB     qT
  //  9..13MB    k_tiles [256 tile][16KB]
  //  13..17MB   v_tiles [256 tile][16KB]
  //  17..49MB   Opart (8 splits, bf16)
  float* part = (float*)(ws);
  float* stat = (float*)(ws + 60 * KB);
  ushort* wqkv = (ushort*)(ws + 64 * KB);
  ushort* wo = (ushort*)(ws + 448 * KB);
  float* mpart = (float*)(ws + 64 * KB);    // overlays wqkv (dead by k_attn)
  float* lpart = (float*)(ws + 576 * KB);
  ushort* xnT = (ushort*)(ws + 1 * MB);
  ushort* qT = (ushort*)(ws + 5 * MB);
  ushort* k_tiles = (ushort*)(ws + 9 * MB);
  ushort* v_tiles = (ushort*)(ws + 13 * MB);
  ushort* Opart = (ushort*)(ws + 17 * MB);

  k_stats1<<<512, 256, 0, stream>>>(x, part);
  k_castw<<<1025, 256, 0, stream>>>(qw, kw, vw, ow, wqkv, wo, part, stat);
  k_norm_t<<<dim3(128, 4), 256, 0, stream>>>(x, gw, gb, stat, xnT);
  k_qkv<<<dim3(128, 12), 256, 0, stream>>>(xnT, wqkv, qbv, kbv, vbv, qT, k_tiles, v_tiles);
  k_attn<<<256, 512, 0, stream>>>(qT, k_tiles, v_tiles, Opart, mpart, lpart);
  k_finalc<<<128, 512, 0, stream>>>(Opart, mpart, lpart, wo, obv, x, gw, gb, stat, out);
}

// Round 15
// 131.877 us; speedup vs baseline: 1.0822x; 1.0822x over previous
//
#include <hip/hip_runtime.h>
#include <hip/hip_bf16.h>
#include <cstdint>

// Problem constants: B=1, C=256, F=8, H=32, W=32 -> N = 8192 spatial.
#define NSP 8192
#define CCH 256
#define KBLK 32
#define NSPLIT 8
#define KEYS_PER_SPLIT 1024
#define NTILES 32  // KEYS_PER_SPLIT / KBLK

typedef __attribute__((ext_vector_type(4))) float f32x4;
typedef __attribute__((ext_vector_type(16))) float f32x16;
typedef __attribute__((ext_vector_type(8))) short bf16x8;
typedef __attribute__((ext_vector_type(2))) unsigned int u32x2;

__device__ __forceinline__ ushort f2bf(float f) {
  union { float f; uint32_t u; } v; v.f = f;
  uint32_t r = (v.u + 0x7FFFu + ((v.u >> 16) & 1u)) >> 16;
  return (ushort)r;
}
__device__ __forceinline__ float bf2f(ushort u) {
  union { uint32_t u; float f; } v; v.u = ((uint32_t)u) << 16; return v.f;
}
__device__ __forceinline__ uint32_t pk2bf(float lo, float hi) {
  __hip_bfloat162 h = __float22bfloat162_rn({lo, hi});
  union { __hip_bfloat162 h; uint32_t u; } c; c.h = h; return c.u;
}

// global -> LDS direct copy, 16B per lane. LDS dest must be wave-uniform base.
__device__ __forceinline__ void gload_lds16(const void* g, void* l) {
  auto gp = (const __attribute__((address_space(1))) uint32_t*)(uintptr_t)g;
  auto lp = (__attribute__((address_space(3))) uint32_t*)(uint32_t)(uintptr_t)l;
  __builtin_amdgcn_global_load_lds(gp, lp, 16, 0, 0);
}

// exchange: swaps hi 32 lanes of a with lo 32 lanes of b
__device__ __forceinline__ void perm32swap(uint32_t& a, uint32_t& b) {
#if __has_builtin(__builtin_amdgcn_permlane32_swap)
  u32x2 r = __builtin_amdgcn_permlane32_swap(a, b, false, false);
  a = r[0]; b = r[1];
#else
  uint32_t sa = __shfl_xor((int)a, 32), sb = __shfl_xor((int)b, 32);
  bool lo = (threadIdx.x & 63) < 32;
  uint32_t na = lo ? a : sb;
  uint32_t nb = lo ? sa : b;
  a = na; b = nb;
#endif
}

// ---------------- K1: per-block partial sum/sumsq over x (2M floats) --------
__global__ __launch_bounds__(256) void k_stats1(const float* __restrict__ x,
                                                float* __restrict__ part) {
  int t = threadIdx.x, b = blockIdx.x;
  float s = 0.f, ss = 0.f;
  const float4* x4 = (const float4*)x;
  for (int i = 0; i < 4; ++i) {
    float4 v = x4[(size_t)i * 131072 + b * 256 + t];
    s += v.x + v.y + v.z + v.w;
    ss += v.x * v.x + v.y * v.y + v.z * v.z + v.w * v.w;
  }
  for (int m = 1; m < 64; m <<= 1) { s += __shfl_xor(s, m); ss += __shfl_xor(ss, m); }
  __shared__ float ls[4], lss[4];
  int w = t >> 6, lane = t & 63;
  if (lane == 0) { ls[w] = s; lss[w] = ss; }
  __syncthreads();
  if (t == 0) {
    part[b * 2 + 0] = ls[0] + ls[1] + ls[2] + ls[3];
    part[b * 2 + 1] = lss[0] + lss[1] + lss[2] + lss[3];
  }
}

// ---------------- K2: cast weights to bf16; block 1024 finalizes stats ------
__global__ __launch_bounds__(256) void k_castw(const float* __restrict__ qw, const float* __restrict__ kw,
                                               const float* __restrict__ vw, const float* __restrict__ ow,
                                               ushort* __restrict__ wqkv, ushort* __restrict__ wo,
                                               const float* __restrict__ part, float* __restrict__ stat) {
  if (blockIdx.x == 1024) {  // stats finalize
    int t = threadIdx.x;
    float s = 0.f, ss = 0.f;
    for (int i = t; i < 512; i += 256) { s += part[i * 2]; ss += part[i * 2 + 1]; }
    for (int m = 1; m < 64; m <<= 1) { s += __shfl_xor(s, m); ss += __shfl_xor(ss, m); }
    __shared__ float ls[4], lss[4];
    int w = t >> 6, lane = t & 63;
    if (lane == 0) { ls[w] = s; lss[w] = ss; }
    __syncthreads();
    if (t == 0) {
      float sum = ls[0] + ls[1] + ls[2] + ls[3];
      float ssum = lss[0] + lss[1] + lss[2] + lss[3];
      float mean = sum * (1.f / 2097152.f);
      float var = ssum * (1.f / 2097152.f) - mean * mean;
      stat[0] = mean;
      stat[1] = rsqrtf(var + 1e-5f);
    }
    return;
  }
  int idx = blockIdx.x * 256 + threadIdx.x;  // 262144 total
  if (idx < 65536) wqkv[idx] = f2bf(qw[idx]);
  else if (idx < 131072) wqkv[idx] = f2bf(kw[idx - 65536]);
  else if (idx < 196608) wqkv[idx] = f2bf(vw[idx - 131072]);
  else wo[idx - 196608] = f2bf(ow[idx - 196608]);
}

// ---------------- K3: normalize + transpose -> xnT bf16 [8192][256] ---------
__global__ __launch_bounds__(256) void k_norm_t(const float* __restrict__ x,
                                                const float* __restrict__ gw, const float* __restrict__ gb,
                                                const float* __restrict__ stat, ushort* __restrict__ xnT) {
  __shared__ float tile[64][66];
  int n0 = blockIdx.x * 64, c0 = blockIdx.y * 64;
  int t = threadIdx.x, colr = t & 63, rq = t >> 6;
  float mean = stat[0], rinv = stat[1];
  for (int rr = 0; rr < 16; ++rr) {
    int row = rr * 4 + rq;  // c-local
    int c = c0 + row;
    float v = x[(size_t)c * NSP + n0 + colr];
    tile[row][colr] = (v - mean) * rinv * gw[c] + gb[c];
  }
  __syncthreads();
  for (int rr = 0; rr < 16; ++rr) {
    int rowW = rr * 4 + rq;  // n-local
    xnT[(size_t)(n0 + rowW) * 256 + c0 + colr] = f2bf(tile[colr][rowW]);
  }
}

// ---------------- K4: QKV GEMM -> qT [8192][256],
//   K packed per key-tile: k_tiles[256 tile][32 s][32 key][8]  (s = chan/8)
//   V packed per key-tile: v_tiles[256 tile][4 slot][256 c][8 m]
__global__ __launch_bounds__(256) void k_qkv(const ushort* __restrict__ xnT, const ushort* __restrict__ wqkv,
                                             const float* __restrict__ qb, const float* __restrict__ kb,
                                             const float* __restrict__ vb,
                                             ushort* __restrict__ qT, ushort* __restrict__ k_tiles,
                                             ushort* __restrict__ v_tiles) {
  __shared__ ushort tile[64][80];  // transpose bounce (160B rows, 16B aligned)
  int nb = blockIdx.x, ob = blockIdx.y;
  int w = threadIdx.x >> 6, lane = threadIdx.x & 63;
  int l16 = lane & 15, kgrp = lane >> 4;
  int n_row = nb * 64 + w * 16 + l16;
  bf16x8 a[8];
  const bf16x8* arow = (const bf16x8*)(xnT + (size_t)n_row * 256);
  for (int ks = 0; ks < 8; ++ks) a[ks] = arow[ks * 4 + kgrp];
  f32x4 acc[4];
  for (int ct = 0; ct < 4; ++ct) {
    int o = ob * 64 + ct * 16 + l16;
    const bf16x8* brow = (const bf16x8*)(wqkv + (size_t)o * 256);
    f32x4 c = {0.f, 0.f, 0.f, 0.f};
    for (int ks = 0; ks < 8; ++ks)
      c = __builtin_amdgcn_mfma_f32_16x16x32_bf16(a[ks], brow[ks * 4 + kgrp], c, 0, 0, 0);
    acc[ct] = c;
  }
  const float SCALE = 0.0625f * 1.44269504088896340736f;  // (1/sqrt(C)) * log2(e)
  if (ob < 4) {  // q outputs: direct scattered write
    for (int ct = 0; ct < 4; ++ct) {
      int o = ob * 64 + ct * 16 + l16;
      for (int r = 0; r < 4; ++r) {
        int n = nb * 64 + w * 16 + kgrp * 4 + r;
        qT[(size_t)n * 256 + o] = f2bf((acc[ct][r] + qb[o]) * SCALE);
      }
    }
  } else if (ob < 8) {  // k outputs: bounce [n][c], emit tile-packed transposed
    for (int ct = 0; ct < 4; ++ct) {
      int o_l = ct * 16 + l16;  // channel-local 0..63
      for (int r = 0; r < 4; ++r) {
        int n_l = w * 16 + kgrp * 4 + r;  // key-local 0..63
        tile[n_l][o_l] = f2bf(acc[ct][r] + kb[(ob - 4) * 64 + o_l]);
      }
    }
    __syncthreads();
    // k_tiles element (tile, s, key, j) = K[key][c = s*8+j]
    for (int j = 0; j < 2; ++j) {
      int idx = j * 256 + threadIdx.x;          // 512 granules of 16B
      int tile_l = idx >> 8, s = (idx >> 5) & 7, key = idx & 31;
      size_t off = (size_t)(nb * 2 + tile_l) * 16384 +
                   (size_t)((ob - 4) * 8 + s) * 512 + key * 16;
      *(uint4*)((char*)k_tiles + off) = *(const uint4*)&tile[tile_l * 32 + key][s * 8];
    }
  } else {  // v outputs: bounce [c][n], emit tile-packed layout, coalesced
    for (int ct = 0; ct < 4; ++ct) {
      int o_l = ct * 16 + l16;
      for (int r = 0; r < 4; ++r) {
        int n_l = w * 16 + kgrp * 4 + r;
        tile[o_l][n_l] = f2bf(acc[ct][r] + vb[(ob - 8) * 64 + o_l]);
      }
    }
    __syncthreads();
    // v_tiles element (t, s, c, m) at ushort offset t*8192 + s*2048 + c*8 + m
    for (int j = 0; j < 2; ++j) {
      int idx = j * 256 + threadIdx.x;          // 512 stores of 16B
      int tile_l = idx >> 8, slot = (idx >> 6) & 3, c_l = idx & 63;
      size_t off = (size_t)(nb * 2 + tile_l) * 8192 + slot * 2048 +
                   (size_t)((ob - 8) * 64 + c_l) * 8;
      *(uint4*)((char*)v_tiles + off * 2) = *(const uint4*)&tile[c_l][tile_l * 32 + slot * 8];
    }
  }
}

// ---------------- K5: flash attention, phase-split pipeline -----------------
// grid 256 = 1 block/CU (32 qblk x 8 splits, split = bid&7 -> XCD-exact).
// 512 threads (8 waves), wave owns 32 q. LDS 64KB: K dbuf + V dbuf (linear).
// Iter tt: phase A = QK(tt) 16 MFMA interleaved 2:1 with PV-half1(tt-1);
// phase B = PV-half2(tt-1) MFMAs overlapped with SPECULATIVE softmax(tt)
// (exp with old m_r -- valid in defer-max fast path; rare slow path fixes up
// by scaling P/sums/acc/l_p by alpha). m_r init 0 keeps speculation finite.
__global__ __launch_bounds__(512, 2) void k_attn(const ushort* __restrict__ qT, const ushort* __restrict__ k_tiles,
                                                 const ushort* __restrict__ v_tiles,
                                                 ushort* __restrict__ Opart, float* __restrict__ mpart,
                                                 float* __restrict__ lpart) {
  __shared__ __align__(16) ushort SMEM[32768];  // 64 KB
  ushort* k_lds = SMEM;          // 2 x 8192: [32 s][32 key][8] (linear tile image)
  ushort* v_lds = SMEM + 16384;  // 2 x 8192: [4 slot][256 c][8 m] (linear tile image)

  int bid = blockIdx.x;
  int split = bid & 7, qblk = bid >> 3;
  int t = threadIdx.x, w = t >> 6, lane = t & 63;
  int l31 = lane & 31, lhi = lane >> 5;
  int q0w = qblk * 256 + w * 32;

  // Q as B-operand fragments: lane holds q=l31, channels cs*16 + lhi*8 + j
  bf16x8 qf[16];
  {
    const char* qbase = (const char*)qT + (size_t)(q0w + l31) * 512;
#pragma unroll
    for (int cs = 0; cs < 16; ++cs)
      qf[cs] = *(const bf16x8*)(qbase + cs * 32 + lhi * 16);
  }

  f32x16 acc[8] = {};                 // O[c][q]: 8 blocks of 32 channels (AGPRs)
  float m_r = 0.f, l_p = 0.f;         // m_r starts 0 for finite speculation
  bf16x8 pf0, pf1;                    // P fragments of the previous tile

  const char* kT_b = (const char*)k_tiles + (size_t)split * KEYS_PER_SPLIT * 512;
  const char* v_b = (const char*)v_tiles + (size_t)split * KEYS_PER_SPLIT * 512;

  auto STAGE_K = [&](int tt) {
    const char* ksrc = kT_b + (size_t)tt * 16384 + w * 2048;
    char* kdst = (char*)(k_lds + (tt & 1) * 8192) + w * 2048;
#pragma unroll
    for (int i = 0; i < 2; ++i)
      gload_lds16(ksrc + i * 1024 + lane * 16, kdst + i * 1024);
  };
  auto STAGE_V = [&](int tt) {
    char* vdst = (char*)(v_lds + (tt & 1) * 8192) + w * 2048;
    const char* vsrc = v_b + (size_t)tt * 16384 + w * 2048;
#pragma unroll
    for (int i = 0; i < 2; ++i)
      gload_lds16(vsrc + i * 1024 + lane * 16, vdst + i * 1024);
  };

  // pack S0 (post-exp) -> pf0, pf1
  auto PACK = [&](const f32x16& S0) {
    union { uint32_t w[4]; bf16x8 v; } u;
    {
      uint32_t x = pk2bf(S0[0], S0[1]), y = pk2bf(S0[4], S0[5]);
      perm32swap(x, y);
      uint32_t x2_ = pk2bf(S0[2], S0[3]), y2 = pk2bf(S0[6], S0[7]);
      perm32swap(x2_, y2);
      u.w[0] = x; u.w[1] = x2_; u.w[2] = y; u.w[3] = y2;
      pf0 = u.v;
    }
    {
      uint32_t x = pk2bf(S0[8], S0[9]), y = pk2bf(S0[12], S0[13]);
      perm32swap(x, y);
      uint32_t x2_ = pk2bf(S0[10], S0[11]), y2 = pk2bf(S0[14], S0[15]);
      perm32swap(x2_, y2);
      u.w[0] = x; u.w[1] = x2_; u.w[2] = y; u.w[3] = y2;
      pf1 = u.v;
    }
  };

  STAGE_K(0);  // prologue

  // ---- iter 0 (peeled): QK(0) + serial softmax(0) ----
  asm volatile("s_waitcnt vmcnt(0) lgkmcnt(0)" ::: "memory");
  __builtin_amdgcn_s_barrier();
  __builtin_amdgcn_sched_barrier(0);
  STAGE_K(1);
  STAGE_V(0);
  {
    const ushort* kl = k_lds;  // buf 0
    f32x16 S0 = {};
    __builtin_amdgcn_s_setprio(1);
#pragma unroll
    for (int cs = 0; cs < 16; ++cs) {
      int slot = cs * 2 + lhi;
      bf16x8 a0 = *(const bf16x8*)(kl + slot * 256 + l31 * 8);
      S0 = __builtin_amdgcn_mfma_f32_32x32x16_bf16(a0, qf[cs], S0, 0, 0, 0);
    }
    __builtin_amdgcn_s_setprio(0);
    float x0 = fmaxf(S0[0], S0[1]), x1 = fmaxf(S0[2], S0[3]);
    float x2 = fmaxf(S0[4], S0[5]), x3 = fmaxf(S0[6], S0[7]);
    float x4 = fmaxf(S0[8], S0[9]), x5 = fmaxf(S0[10], S0[11]);
    float x6 = fmaxf(S0[12], S0[13]), x7 = fmaxf(S0[14], S0[15]);
    float pm = fmaxf(fmaxf(fmaxf(x0, x1), fmaxf(x2, x3)),
                     fmaxf(fmaxf(x4, x5), fmaxf(x6, x7)));
    pm = fmaxf(pm, __shfl_xor(pm, 32));
    if (!__all(pm <= m_r + 8.f)) m_r = fmaxf(m_r, pm);  // acc=0, l_p=0: no alpha
    float t0s = 0.f, t1s = 0.f;
#pragma unroll
    for (int r = 0; r < 16; ++r) {
      S0[r] = __builtin_amdgcn_exp2f(S0[r] - m_r);
      if (r & 1) t1s += S0[r]; else t0s += S0[r];
    }
    l_p = t0s + t1s;
    PACK(S0);
  }

#pragma unroll 1
  for (int tt = 1; tt < NTILES; ++tt) {
    asm volatile("s_waitcnt vmcnt(0) lgkmcnt(0)" ::: "memory");
    __builtin_amdgcn_s_barrier();
    __builtin_amdgcn_sched_barrier(0);
    if (tt + 1 < NTILES) STAGE_K(tt + 1);
    STAGE_V(tt);

    const ushort* kl = k_lds + (tt & 1) * 8192;
    const ushort* vl = v_lds + ((tt - 1) & 1) * 8192;
    f32x16 S0 = {};
    __builtin_amdgcn_s_setprio(1);
    // ---- phase A: QK(tt) 2:1 with PV-half1(tt-1) ----
#pragma unroll
    for (int cb = 0; cb < 8; ++cb) {
      bf16x8 va0 = *(const bf16x8*)(vl + lhi * 2048 + (cb * 32 + l31) * 8);
      acc[cb] = __builtin_amdgcn_mfma_f32_32x32x16_bf16(va0, pf0, acc[cb], 0, 0, 0);
      {
        bf16x8 ka = *(const bf16x8*)(kl + (4 * cb + lhi) * 256 + l31 * 8);
        S0 = __builtin_amdgcn_mfma_f32_32x32x16_bf16(ka, qf[2 * cb], S0, 0, 0, 0);
      }
      {
        bf16x8 ka = *(const bf16x8*)(kl + (4 * cb + 2 + lhi) * 256 + l31 * 8);
        S0 = __builtin_amdgcn_mfma_f32_32x32x16_bf16(ka, qf[2 * cb + 1], S0, 0, 0, 0);
      }
    }
    // ---- phase B: PV-half2(tt-1) || speculative softmax(tt) ----
    float pm0 = -1e30f, pm1 = -1e30f;
    float t0s = 0.f, t1s = 0.f;
#pragma unroll
    for (int cb = 0; cb < 8; ++cb) {
      bf16x8 va1 = *(const bf16x8*)(vl + (2 + lhi) * 2048 + (cb * 32 + l31) * 8);
      acc[cb] = __builtin_amdgcn_mfma_f32_32x32x16_bf16(va1, pf1, acc[cb], 0, 0, 0);
      pm0 = fmaxf(pm0, S0[2 * cb]);
      S0[2 * cb] = __builtin_amdgcn_exp2f(S0[2 * cb] - m_r);
      t0s += S0[2 * cb];
      pm1 = fmaxf(pm1, S0[2 * cb + 1]);
      S0[2 * cb + 1] = __builtin_amdgcn_exp2f(S0[2 * cb + 1] - m_r);
      t1s += S0[2 * cb + 1];
    }
    __builtin_amdgcn_s_setprio(0);
    // ---- tail: max check + rare fixup + pack ----
    float pm = fmaxf(pm0, pm1);
    pm = fmaxf(pm, __shfl_xor(pm, 32));
    if (!__all(pm <= m_r + 8.f)) {   // slow path (rare): re-scale speculation
      float mn = fmaxf(m_r, pm);
      float alpha = __builtin_amdgcn_exp2f(m_r - mn);
      m_r = mn;
      l_p *= alpha; t0s *= alpha; t1s *= alpha;
#pragma unroll
      for (int r = 0; r < 16; ++r) S0[r] *= alpha;
#pragma unroll
      for (int cb = 0; cb < 8; ++cb)
#pragma unroll
        for (int r = 0; r < 16; ++r) acc[cb][r] *= alpha;
    }
    l_p += t0s + t1s;
    PACK(S0);
  }

  // ---- drain pipeline: PV(NTILES-1), both halves ----
  asm volatile("s_waitcnt vmcnt(0) lgkmcnt(0)" ::: "memory");
  __builtin_amdgcn_s_barrier();
  {
    const ushort* vl = v_lds + ((NTILES - 1) & 1) * 8192;
    __builtin_amdgcn_s_setprio(1);
#pragma unroll
    for (int cb = 0; cb < 8; ++cb) {
      bf16x8 va0 = *(const bf16x8*)(vl + lhi * 2048 + (cb * 32 + l31) * 8);
      acc[cb] = __builtin_amdgcn_mfma_f32_32x32x16_bf16(va0, pf0, acc[cb], 0, 0, 0);
      bf16x8 va1 = *(const bf16x8*)(vl + (2 + lhi) * 2048 + (cb * 32 + l31) * 8);
      acc[cb] = __builtin_amdgcn_mfma_f32_32x32x16_bf16(va1, pf1, acc[cb], 0, 0, 0);
    }
    __builtin_amdgcn_s_setprio(0);
  }

  // all waves done with LDS before reusing it as epilogue scratch
  asm volatile("s_waitcnt lgkmcnt(0)" ::: "memory");
  __builtin_amdgcn_s_barrier();

  // ---- epilogue: l reduce, O -> LDS transpose (64-c chunks) -> coalesced ----
  float l_tot = l_p + __shfl_xor(l_p, 32);

  // per-wave scratch: 32 q-rows x 144B (64 c x 2B + 16B pad); 8 waves = 36KB
  char* eb = (char*)SMEM + w * 4608;
  size_t gq0 = (size_t)split * NSP + q0w;
#pragma unroll
  for (int ch = 0; ch < 4; ++ch) {
#pragma unroll
    for (int cb2 = 0; cb2 < 2; ++cb2) {
      int cb = ch * 2 + cb2;
#pragma unroll
      for (int g = 0; g < 4; ++g) {
        int cl = cb2 * 32 + g * 8 + 4 * lhi;
        *(uint32_t*)(eb + l31 * 144 + cl * 2) = pk2bf(acc[cb][g * 4 + 0], acc[cb][g * 4 + 1]);
        *(uint32_t*)(eb + l31 * 144 + cl * 2 + 4) = pk2bf(acc[cb][g * 4 + 2], acc[cb][g * 4 + 3]);
      }
    }
    asm volatile("s_waitcnt lgkmcnt(0)" ::: "memory");
    __builtin_amdgcn_sched_barrier(0);
#pragma unroll
    for (int i = 0; i < 4; ++i) {
      int flat = i * 1024 + lane * 16;
      int qr = flat >> 7, off = flat & 127;
      uint4 val = *(const uint4*)(eb + qr * 144 + off);
      *(uint4*)((char*)Opart + (gq0 + qr) * 512 + ch * 128 + off) = val;
    }
    asm volatile("s_waitcnt lgkmcnt(0)" ::: "memory");
    __builtin_amdgcn_sched_barrier(0);
  }
  if (lane < 32) {
    int q = q0w + l31;
    mpart[split * NSP + q] = m_r;
    lpart[split * NSP + q] = l_tot;
  }
}

// ---------------- K6: combine split partials -> attT bf16 [8192][256] -------
// 8 q-rows per block; each thread handles 8 channels via bf16x8 (vectorized).
__global__ __launch_bounds__(256) void k_combine(const ushort* __restrict__ Opart,
                                                 const float* __restrict__ mpart,
                                                 const float* __restrict__ lpart,
                                                 ushort* __restrict__ attT) {
  int q = blockIdx.x * 8 + (threadIdx.x >> 5);
  int c8 = threadIdx.x & 31;  // channels c8*8 .. c8*8+7
  float M = -1e30f;
#pragma unroll
  for (int s = 0; s < NSPLIT; ++s) M = fmaxf(M, mpart[s * NSP + q]);
  float L = 0.f;
  float av[8] = {};
#pragma unroll
  for (int s = 0; s < NSPLIT; ++s) {
    float ws = __builtin_amdgcn_exp2f(mpart[s * NSP + q] - M);
    L += ws * lpart[s * NSP + q];
    bf16x8 o = *(const bf16x8*)(Opart + ((size_t)s * NSP + q) * 256 + c8 * 8);
#pragma unroll
    for (int j = 0; j < 8; ++j) av[j] += ws * bf2f((ushort)o[j]);
  }
  float rL = 1.f / L;
  uint4 outv;
  outv.x = pk2bf(av[0] * rL, av[1] * rL);
  outv.y = pk2bf(av[2] * rL, av[3] * rL);
  outv.z = pk2bf(av[4] * rL, av[5] * rL);
  outv.w = pk2bf(av[6] * rL, av[7] * rL);
  *(uint4*)(attT + (size_t)q * 256 + c8 * 8) = outv;
}

// ---------------- K7: out = xn + ow @ att + ob ------------------------------
__global__ __launch_bounds__(256) void k_final(const ushort* __restrict__ attT, const ushort* __restrict__ wo,
                                               const float* __restrict__ ob, const float* __restrict__ x,
                                               const float* __restrict__ gw, const float* __restrict__ gb,
                                               const float* __restrict__ stat, float* __restrict__ out) {
  int nb = blockIdx.x, obk = blockIdx.y;
  int w = threadIdx.x >> 6, lane = threadIdx.x & 63;
  int l16 = lane & 15, kgrp = lane >> 4;
  int orow = obk * 64 + w * 16 + l16;
  bf16x8 a[8];
  const bf16x8* arow = (const bf16x8*)(wo + (size_t)orow * 256);
  for (int ks = 0; ks < 8; ++ks) a[ks] = arow[ks * 4 + kgrp];
  float mean = stat[0], rinv = stat[1];
  f32x4 acc[4];
  for (int ct = 0; ct < 4; ++ct) {
    int n = nb * 64 + ct * 16 + l16;
    const bf16x8* brow = (const bf16x8*)(attT + (size_t)n * 256);
    f32x4 c = {0.f, 0.f, 0.f, 0.f};
    for (int ks = 0; ks < 8; ++ks)
      c = __builtin_amdgcn_mfma_f32_16x16x32_bf16(a[ks], brow[ks * 4 + kgrp], c, 0, 0, 0);
    acc[ct] = c;
  }
  for (int ct = 0; ct < 4; ++ct) {
    for (int r = 0; r < 4; ++r) {
      int o = obk * 64 + w * 16 + kgrp * 4 + r;
      int n = nb * 64 + ct * 16 + l16;
      float xv = x[(size_t)o * NSP + n];
      float xn = (xv - mean) * rinv * gw[o] + gb[o];
      out[(size_t)o * NSP + n] = xn + acc[ct][r] + ob[o];
    }
  }
}

extern "C" void kernel_launch(void* const* d_in, const int* in_sizes, int n_in,
                              void* d_out, int out_size, void* d_ws, size_t ws_size,
                              hipStream_t stream) {
  const float* x = (const float*)d_in[0];
  const float* gw = (const float*)d_in[1];
  const float* gb = (const float*)d_in[2];
  const float* qw = (const float*)d_in[3];
  const float* qbv = (const float*)d_in[4];
  const float* kw = (const float*)d_in[5];
  const float* kbv = (const float*)d_in[6];
  const float* vw = (const float*)d_in[7];
  const float* vbv = (const float*)d_in[8];
  const float* ow = (const float*)d_in[9];
  const float* obv = (const float*)d_in[10];
  float* out = (float*)d_out;
  char* ws = (char*)d_ws;
  const size_t KB = 1024, MB = 1048576;
  // region plan (high-water 49 MB):
  //  0..4K      part
  //  60K        stat
  //  64..448K   wqkv (dead after k_qkv) -> mpart (256K) overlays
  //  448..576K  wo (live until k_final)
  //  576..832K  lpart
  //  1..5MB     xnT (k_norm_t->k_qkv) -> attT (k_combine->k_final)
  //  5..9MB     qT
  //  9..13MB    k_tiles [256 tile][16KB]
  //  13..17MB   v_tiles [256 tile][16KB]
  //  17..49MB   Opart (8 splits, bf16)
  float* part = (float*)(ws);
  float* stat = (float*)(ws + 60 * KB);
  ushort* wqkv = (ushort*)(ws + 64 * KB);
  ushort* wo = (ushort*)(ws + 448 * KB);
  float* mpart = (float*)(ws + 64 * KB);    // overlays wqkv (dead by k_attn)
  float* lpart = (float*)(ws + 576 * KB);
  ushort* xnT = (ushort*)(ws + 1 * MB);
  ushort* qT = (ushort*)(ws + 5 * MB);
  ushort* k_tiles = (ushort*)(ws + 9 * MB);
  ushort* v_tiles = (ushort*)(ws + 13 * MB);
  ushort* Opart = (ushort*)(ws + 17 * MB);
  ushort* attT = xnT;  // alias: xnT dead after k_qkv

  k_stats1<<<512, 256, 0, stream>>>(x, part);
  k_castw<<<1025, 256, 0, stream>>>(qw, kw, vw, ow, wqkv, wo, part, stat);
  k_norm_t<<<dim3(128, 4), 256, 0, stream>>>(x, gw, gb, stat, xnT);
  k_qkv<<<dim3(128, 12), 256, 0, stream>>>(xnT, wqkv, qbv, kbv, vbv, qT, k_tiles, v_tiles);
  k_attn<<<256, 512, 0, stream>>>(qT, k_tiles, v_tiles, Opart, mpart, lpart);
  k_combine<<<NSP / 8, 256, 0, stream>>>(Opart, mpart, lpart, attT);
  k_final<<<dim3(128, 4), 256, 0, stream>>>(attT, wo, obv, x, gw, gb, stat, out);
}

// Round 16
// 130.096 us; speedup vs baseline: 1.0970x; 1.0137x over previous
//
#include <hip/hip_runtime.h>
#include <hip/hip_bf16.h>
#include <cstdint>

// Problem constants: B=1, C=256, F=8, H=32, W=32 -> N = 8192 spatial.
#define NSP 8192
#define CCH 256
#define KBLK 32
#define NSPLIT 8
#define KEYS_PER_SPLIT 1024
#define NTILES 32  // KEYS_PER_SPLIT / KBLK

typedef __attribute__((ext_vector_type(4))) float f32x4;
typedef __attribute__((ext_vector_type(16))) float f32x16;
typedef __attribute__((ext_vector_type(8))) short bf16x8;
typedef __attribute__((ext_vector_type(2))) unsigned int u32x2;

__device__ __forceinline__ ushort f2bf(float f) {
  union { float f; uint32_t u; } v; v.f = f;
  uint32_t r = (v.u + 0x7FFFu + ((v.u >> 16) & 1u)) >> 16;
  return (ushort)r;
}
__device__ __forceinline__ float bf2f(ushort u) {
  union { uint32_t u; float f; } v; v.u = ((uint32_t)u) << 16; return v.f;
}
__device__ __forceinline__ uint32_t pk2bf(float lo, float hi) {
  __hip_bfloat162 h = __float22bfloat162_rn({lo, hi});
  union { __hip_bfloat162 h; uint32_t u; } c; c.h = h; return c.u;
}

// global -> LDS direct copy, 16B per lane. LDS dest must be wave-uniform base.
__device__ __forceinline__ void gload_lds16(const void* g, void* l) {
  auto gp = (const __attribute__((address_space(1))) uint32_t*)(uintptr_t)g;
  auto lp = (__attribute__((address_space(3))) uint32_t*)(uint32_t)(uintptr_t)l;
  __builtin_amdgcn_global_load_lds(gp, lp, 16, 0, 0);
}

// exchange: swaps hi 32 lanes of a with lo 32 lanes of b
__device__ __forceinline__ void perm32swap(uint32_t& a, uint32_t& b) {
#if __has_builtin(__builtin_amdgcn_permlane32_swap)
  u32x2 r = __builtin_amdgcn_permlane32_swap(a, b, false, false);
  a = r[0]; b = r[1];
#else
  uint32_t sa = __shfl_xor((int)a, 32), sb = __shfl_xor((int)b, 32);
  bool lo = (threadIdx.x & 63) < 32;
  uint32_t na = lo ? a : sb;
  uint32_t nb = lo ? sa : b;
  a = na; b = nb;
#endif
}

// ---------------- K1: fused stats partials + weight cast --------------------
// blocks 0..511: per-block partial sum/sumsq of x. blocks 512..1535: cast
// qw/kw/vw/ow fp32 -> bf16. Independent work, overlapped in one launch.
__global__ __launch_bounds__(256) void k_pre(const float* __restrict__ x,
                                             float* __restrict__ part,
                                             const float* __restrict__ qw, const float* __restrict__ kw,
                                             const float* __restrict__ vw, const float* __restrict__ ow,
                                             ushort* __restrict__ wqkv, ushort* __restrict__ wo) {
  int b = blockIdx.x, t = threadIdx.x;
  if (b < 512) {
    float s = 0.f, ss = 0.f;
    const float4* x4 = (const float4*)x;
    for (int i = 0; i < 4; ++i) {
      float4 v = x4[(size_t)i * 131072 + b * 256 + t];
      s += v.x + v.y + v.z + v.w;
      ss += v.x * v.x + v.y * v.y + v.z * v.z + v.w * v.w;
    }
    for (int m = 1; m < 64; m <<= 1) { s += __shfl_xor(s, m); ss += __shfl_xor(ss, m); }
    __shared__ float ls[4], lss[4];
    int w = t >> 6, lane = t & 63;
    if (lane == 0) { ls[w] = s; lss[w] = ss; }
    __syncthreads();
    if (t == 0) {
      part[b * 2 + 0] = ls[0] + ls[1] + ls[2] + ls[3];
      part[b * 2 + 1] = lss[0] + lss[1] + lss[2] + lss[3];
    }
    return;
  }
  int idx = (b - 512) * 256 + t;  // 262144 total
  if (idx < 65536) wqkv[idx] = f2bf(qw[idx]);
  else if (idx < 131072) wqkv[idx] = f2bf(kw[idx - 65536]);
  else if (idx < 196608) wqkv[idx] = f2bf(vw[idx - 131072]);
  else wo[idx - 196608] = f2bf(ow[idx - 196608]);
}

// in-block stats finalize: wave 0 reduces part[1024] -> sh2 = {mean, rinv}
__device__ __forceinline__ void stat_finalize(const float* __restrict__ part,
                                              int t, float* sh2) {
  if (t < 64) {
    float s = 0.f, ss = 0.f;
#pragma unroll
    for (int i = 0; i < 8; ++i) {
      int p = t + i * 64;
      s += part[2 * p]; ss += part[2 * p + 1];
    }
    for (int m = 1; m < 64; m <<= 1) { s += __shfl_xor(s, m); ss += __shfl_xor(ss, m); }
    if (t == 0) {
      float mean = s * (1.f / 2097152.f);
      float var = ss * (1.f / 2097152.f) - mean * mean;
      sh2[0] = mean;
      sh2[1] = rsqrtf(var + 1e-5f);
    }
  }
}

// ---------------- K2: normalize + transpose -> xnT bf16 [8192][256] ---------
__global__ __launch_bounds__(256) void k_norm_t(const float* __restrict__ x,
                                                const float* __restrict__ gw, const float* __restrict__ gb,
                                                const float* __restrict__ part, ushort* __restrict__ xnT) {
  __shared__ float tile[64][66];
  __shared__ float sstat[2];
  int n0 = blockIdx.x * 64, c0 = blockIdx.y * 64;
  int t = threadIdx.x, colr = t & 63, rq = t >> 6;
  stat_finalize(part, t, sstat);
  __syncthreads();
  float mean = sstat[0], rinv = sstat[1];
  for (int rr = 0; rr < 16; ++rr) {
    int row = rr * 4 + rq;  // c-local
    int c = c0 + row;
    float v = x[(size_t)c * NSP + n0 + colr];
    tile[row][colr] = (v - mean) * rinv * gw[c] + gb[c];
  }
  __syncthreads();
  for (int rr = 0; rr < 16; ++rr) {
    int rowW = rr * 4 + rq;  // n-local
    xnT[(size_t)(n0 + rowW) * 256 + c0 + colr] = f2bf(tile[colr][rowW]);
  }
}

// ---------------- K3: QKV GEMM -> qT [8192][256],
//   K packed per key-tile: k_tiles[256 tile][32 s][32 key][8]  (s = chan/8)
//   V packed per key-tile: v_tiles[256 tile][4 slot][256 c][8 m]
__global__ __launch_bounds__(256) void k_qkv(const ushort* __restrict__ xnT, const ushort* __restrict__ wqkv,
                                             const float* __restrict__ qb, const float* __restrict__ kb,
                                             const float* __restrict__ vb,
                                             ushort* __restrict__ qT, ushort* __restrict__ k_tiles,
                                             ushort* __restrict__ v_tiles) {
  __shared__ ushort tile[64][80];  // transpose bounce (160B rows, 16B aligned)
  int nb = blockIdx.x, ob = blockIdx.y;
  int w = threadIdx.x >> 6, lane = threadIdx.x & 63;
  int l16 = lane & 15, kgrp = lane >> 4;
  int n_row = nb * 64 + w * 16 + l16;
  bf16x8 a[8];
  const bf16x8* arow = (const bf16x8*)(xnT + (size_t)n_row * 256);
  for (int ks = 0; ks < 8; ++ks) a[ks] = arow[ks * 4 + kgrp];
  f32x4 acc[4];
  for (int ct = 0; ct < 4; ++ct) {
    int o = ob * 64 + ct * 16 + l16;
    const bf16x8* brow = (const bf16x8*)(wqkv + (size_t)o * 256);
    f32x4 c = {0.f, 0.f, 0.f, 0.f};
    for (int ks = 0; ks < 8; ++ks)
      c = __builtin_amdgcn_mfma_f32_16x16x32_bf16(a[ks], brow[ks * 4 + kgrp], c, 0, 0, 0);
    acc[ct] = c;
  }
  const float SCALE = 0.0625f * 1.44269504088896340736f;  // (1/sqrt(C)) * log2(e)
  if (ob < 4) {  // q outputs: direct scattered write
    for (int ct = 0; ct < 4; ++ct) {
      int o = ob * 64 + ct * 16 + l16;
      for (int r = 0; r < 4; ++r) {
        int n = nb * 64 + w * 16 + kgrp * 4 + r;
        qT[(size_t)n * 256 + o] = f2bf((acc[ct][r] + qb[o]) * SCALE);
      }
    }
  } else if (ob < 8) {  // k outputs: bounce [n][c], emit tile-packed transposed
    for (int ct = 0; ct < 4; ++ct) {
      int o_l = ct * 16 + l16;  // channel-local 0..63
      for (int r = 0; r < 4; ++r) {
        int n_l = w * 16 + kgrp * 4 + r;  // key-local 0..63
        tile[n_l][o_l] = f2bf(acc[ct][r] + kb[(ob - 4) * 64 + o_l]);
      }
    }
    __syncthreads();
    // k_tiles element (tile, s, key, j) = K[key][c = s*8+j]
    for (int j = 0; j < 2; ++j) {
      int idx = j * 256 + threadIdx.x;          // 512 granules of 16B
      int tile_l = idx >> 8, s = (idx >> 5) & 7, key = idx & 31;
      size_t off = (size_t)(nb * 2 + tile_l) * 16384 +
                   (size_t)((ob - 4) * 8 + s) * 512 + key * 16;
      *(uint4*)((char*)k_tiles + off) = *(const uint4*)&tile[tile_l * 32 + key][s * 8];
    }
  } else {  // v outputs: bounce [c][n], emit tile-packed layout, coalesced
    for (int ct = 0; ct < 4; ++ct) {
      int o_l = ct * 16 + l16;
      for (int r = 0; r < 4; ++r) {
        int n_l = w * 16 + kgrp * 4 + r;
        tile[o_l][n_l] = f2bf(acc[ct][r] + vb[(ob - 8) * 64 + o_l]);
      }
    }
    __syncthreads();
    // v_tiles element (t, s, c, m) at ushort offset t*8192 + s*2048 + c*8 + m
    for (int j = 0; j < 2; ++j) {
      int idx = j * 256 + threadIdx.x;          // 512 stores of 16B
      int tile_l = idx >> 8, slot = (idx >> 6) & 3, c_l = idx & 63;
      size_t off = (size_t)(nb * 2 + tile_l) * 8192 + slot * 2048 +
                   (size_t)((ob - 8) * 64 + c_l) * 8;
      *(uint4*)((char*)v_tiles + off * 2) = *(const uint4*)&tile[c_l][tile_l * 32 + slot * 8];
    }
  }
}

// ---------------- K4: flash attention, phase-split pipeline -----------------
// grid 256 = 1 block/CU (32 qblk x 8 splits, split = bid&7 -> XCD-exact).
// 512 threads (8 waves), wave owns 32 q. LDS 64KB: K dbuf + V dbuf (linear).
// Iter tt: phase A = QK(tt) 16 MFMA interleaved 2:1 with PV-half1(tt-1);
// phase B = PV-half2(tt-1) MFMAs overlapped with SPECULATIVE softmax(tt)
// (exp with old m_r -- valid in defer-max fast path; rare slow path fixes up
// by scaling P/sums/acc/l_p by alpha). m_r init 0 keeps speculation finite.
__global__ __launch_bounds__(512, 2) void k_attn(const ushort* __restrict__ qT, const ushort* __restrict__ k_tiles,
                                                 const ushort* __restrict__ v_tiles,
                                                 ushort* __restrict__ Opart, float* __restrict__ mpart,
                                                 float* __restrict__ lpart) {
  __shared__ __align__(16) ushort SMEM[32768];  // 64 KB
  ushort* k_lds = SMEM;          // 2 x 8192: [32 s][32 key][8] (linear tile image)
  ushort* v_lds = SMEM + 16384;  // 2 x 8192: [4 slot][256 c][8 m] (linear tile image)

  int bid = blockIdx.x;
  int split = bid & 7, qblk = bid >> 3;
  int t = threadIdx.x, w = t >> 6, lane = t & 63;
  int l31 = lane & 31, lhi = lane >> 5;
  int q0w = qblk * 256 + w * 32;

  // Q as B-operand fragments: lane holds q=l31, channels cs*16 + lhi*8 + j
  bf16x8 qf[16];
  {
    const char* qbase = (const char*)qT + (size_t)(q0w + l31) * 512;
#pragma unroll
    for (int cs = 0; cs < 16; ++cs)
      qf[cs] = *(const bf16x8*)(qbase + cs * 32 + lhi * 16);
  }

  f32x16 acc[8] = {};                 // O[c][q]: 8 blocks of 32 channels (AGPRs)
  float m_r = 0.f, l_p = 0.f;         // m_r starts 0 for finite speculation
  bf16x8 pf0, pf1;                    // P fragments of the previous tile

  const char* kT_b = (const char*)k_tiles + (size_t)split * KEYS_PER_SPLIT * 512;
  const char* v_b = (const char*)v_tiles + (size_t)split * KEYS_PER_SPLIT * 512;

  auto STAGE_K = [&](int tt) {
    const char* ksrc = kT_b + (size_t)tt * 16384 + w * 2048;
    char* kdst = (char*)(k_lds + (tt & 1) * 8192) + w * 2048;
#pragma unroll
    for (int i = 0; i < 2; ++i)
      gload_lds16(ksrc + i * 1024 + lane * 16, kdst + i * 1024);
  };
  auto STAGE_V = [&](int tt) {
    char* vdst = (char*)(v_lds + (tt & 1) * 8192) + w * 2048;
    const char* vsrc = v_b + (size_t)tt * 16384 + w * 2048;
#pragma unroll
    for (int i = 0; i < 2; ++i)
      gload_lds16(vsrc + i * 1024 + lane * 16, vdst + i * 1024);
  };

  // pack S0 (post-exp) -> pf0, pf1
  auto PACK = [&](const f32x16& S0) {
    union { uint32_t w[4]; bf16x8 v; } u;
    {
      uint32_t x = pk2bf(S0[0], S0[1]), y = pk2bf(S0[4], S0[5]);
      perm32swap(x, y);
      uint32_t x2_ = pk2bf(S0[2], S0[3]), y2 = pk2bf(S0[6], S0[7]);
      perm32swap(x2_, y2);
      u.w[0] = x; u.w[1] = x2_; u.w[2] = y; u.w[3] = y2;
      pf0 = u.v;
    }
    {
      uint32_t x = pk2bf(S0[8], S0[9]), y = pk2bf(S0[12], S0[13]);
      perm32swap(x, y);
      uint32_t x2_ = pk2bf(S0[10], S0[11]), y2 = pk2bf(S0[14], S0[15]);
      perm32swap(x2_, y2);
      u.w[0] = x; u.w[1] = x2_; u.w[2] = y; u.w[3] = y2;
      pf1 = u.v;
    }
  };

  STAGE_K(0);  // prologue

  // ---- iter 0 (peeled): QK(0) + serial softmax(0) ----
  asm volatile("s_waitcnt vmcnt(0) lgkmcnt(0)" ::: "memory");
  __builtin_amdgcn_s_barrier();
  __builtin_amdgcn_sched_barrier(0);
  STAGE_K(1);
  STAGE_V(0);
  {
    const ushort* kl = k_lds;  // buf 0
    f32x16 S0 = {};
    __builtin_amdgcn_s_setprio(1);
#pragma unroll
    for (int cs = 0; cs < 16; ++cs) {
      int slot = cs * 2 + lhi;
      bf16x8 a0 = *(const bf16x8*)(kl + slot * 256 + l31 * 8);
      S0 = __builtin_amdgcn_mfma_f32_32x32x16_bf16(a0, qf[cs], S0, 0, 0, 0);
    }
    __builtin_amdgcn_s_setprio(0);
    float x0 = fmaxf(S0[0], S0[1]), x1 = fmaxf(S0[2], S0[3]);
    float x2 = fmaxf(S0[4], S0[5]), x3 = fmaxf(S0[6], S0[7]);
    float x4 = fmaxf(S0[8], S0[9]), x5 = fmaxf(S0[10], S0[11]);
    float x6 = fmaxf(S0[12], S0[13]), x7 = fmaxf(S0[14], S0[15]);
    float pm = fmaxf(fmaxf(fmaxf(x0, x1), fmaxf(x2, x3)),
                     fmaxf(fmaxf(x4, x5), fmaxf(x6, x7)));
    pm = fmaxf(pm, __shfl_xor(pm, 32));
    if (!__all(pm <= m_r + 8.f)) m_r = fmaxf(m_r, pm);  // acc=0, l_p=0: no alpha
    float t0s = 0.f, t1s = 0.f;
#pragma unroll
    for (int r = 0; r < 16; ++r) {
      S0[r] = __builtin_amdgcn_exp2f(S0[r] - m_r);
      if (r & 1) t1s += S0[r]; else t0s += S0[r];
    }
    l_p = t0s + t1s;
    PACK(S0);
  }

#pragma unroll 1
  for (int tt = 1; tt < NTILES; ++tt) {
    asm volatile("s_waitcnt vmcnt(0) lgkmcnt(0)" ::: "memory");
    __builtin_amdgcn_s_barrier();
    __builtin_amdgcn_sched_barrier(0);
    if (tt + 1 < NTILES) STAGE_K(tt + 1);
    STAGE_V(tt);

    const ushort* kl = k_lds + (tt & 1) * 8192;
    const ushort* vl = v_lds + ((tt - 1) & 1) * 8192;
    f32x16 S0 = {};
    __builtin_amdgcn_s_setprio(1);
    // ---- phase A: QK(tt) 2:1 with PV-half1(tt-1) ----
#pragma unroll
    for (int cb = 0; cb < 8; ++cb) {
      bf16x8 va0 = *(const bf16x8*)(vl + lhi * 2048 + (cb * 32 + l31) * 8);
      acc[cb] = __builtin_amdgcn_mfma_f32_32x32x16_bf16(va0, pf0, acc[cb], 0, 0, 0);
      {
        bf16x8 ka = *(const bf16x8*)(kl + (4 * cb + lhi) * 256 + l31 * 8);
        S0 = __builtin_amdgcn_mfma_f32_32x32x16_bf16(ka, qf[2 * cb], S0, 0, 0, 0);
      }
      {
        bf16x8 ka = *(const bf16x8*)(kl + (4 * cb + 2 + lhi) * 256 + l31 * 8);
        S0 = __builtin_amdgcn_mfma_f32_32x32x16_bf16(ka, qf[2 * cb + 1], S0, 0, 0, 0);
      }
    }
    // ---- phase B: PV-half2(tt-1) || speculative softmax(tt) ----
    float pm0 = -1e30f, pm1 = -1e30f;
    float t0s = 0.f, t1s = 0.f;
#pragma unroll
    for (int cb = 0; cb < 8; ++cb) {
      bf16x8 va1 = *(const bf16x8*)(vl + (2 + lhi) * 2048 + (cb * 32 + l31) * 8);
      acc[cb] = __builtin_amdgcn_mfma_f32_32x32x16_bf16(va1, pf1, acc[cb], 0, 0, 0);
      pm0 = fmaxf(pm0, S0[2 * cb]);
      S0[2 * cb] = __builtin_amdgcn_exp2f(S0[2 * cb] - m_r);
      t0s += S0[2 * cb];
      pm1 = fmaxf(pm1, S0[2 * cb + 1]);
      S0[2 * cb + 1] = __builtin_amdgcn_exp2f(S0[2 * cb + 1] - m_r);
      t1s += S0[2 * cb + 1];
    }
    __builtin_amdgcn_s_setprio(0);
    // ---- tail: max check + rare fixup + pack ----
    float pm = fmaxf(pm0, pm1);
    pm = fmaxf(pm, __shfl_xor(pm, 32));
    if (!__all(pm <= m_r + 8.f)) {   // slow path (rare): re-scale speculation
      float mn = fmaxf(m_r, pm);
      float alpha = __builtin_amdgcn_exp2f(m_r - mn);
      m_r = mn;
      l_p *= alpha; t0s *= alpha; t1s *= alpha;
#pragma unroll
      for (int r = 0; r < 16; ++r) S0[r] *= alpha;
#pragma unroll
      for (int cb = 0; cb < 8; ++cb)
#pragma unroll
        for (int r = 0; r < 16; ++r) acc[cb][r] *= alpha;
    }
    l_p += t0s + t1s;
    PACK(S0);
  }

  // ---- drain pipeline: PV(NTILES-1), both halves ----
  asm volatile("s_waitcnt vmcnt(0) lgkmcnt(0)" ::: "memory");
  __builtin_amdgcn_s_barrier();
  {
    const ushort* vl = v_lds + ((NTILES - 1) & 1) * 8192;
    __builtin_amdgcn_s_setprio(1);
#pragma unroll
    for (int cb = 0; cb < 8; ++cb) {
      bf16x8 va0 = *(const bf16x8*)(vl + lhi * 2048 + (cb * 32 + l31) * 8);
      acc[cb] = __builtin_amdgcn_mfma_f32_32x32x16_bf16(va0, pf0, acc[cb], 0, 0, 0);
      bf16x8 va1 = *(const bf16x8*)(vl + (2 + lhi) * 2048 + (cb * 32 + l31) * 8);
      acc[cb] = __builtin_amdgcn_mfma_f32_32x32x16_bf16(va1, pf1, acc[cb], 0, 0, 0);
    }
    __builtin_amdgcn_s_setprio(0);
  }

  // all waves done with LDS before reusing it as epilogue scratch
  asm volatile("s_waitcnt lgkmcnt(0)" ::: "memory");
  __builtin_amdgcn_s_barrier();

  // ---- epilogue: l reduce, O -> LDS transpose (64-c chunks) -> coalesced ----
  float l_tot = l_p + __shfl_xor(l_p, 32);

  // per-wave scratch: 32 q-rows x 144B (64 c x 2B + 16B pad); 8 waves = 36KB
  char* eb = (char*)SMEM + w * 4608;
  size_t gq0 = (size_t)split * NSP + q0w;
#pragma unroll
  for (int ch = 0; ch < 4; ++ch) {
#pragma unroll
    for (int cb2 = 0; cb2 < 2; ++cb2) {
      int cb = ch * 2 + cb2;
#pragma unroll
      for (int g = 0; g < 4; ++g) {
        int cl = cb2 * 32 + g * 8 + 4 * lhi;
        *(uint32_t*)(eb + l31 * 144 + cl * 2) = pk2bf(acc[cb][g * 4 + 0], acc[cb][g * 4 + 1]);
        *(uint32_t*)(eb + l31 * 144 + cl * 2 + 4) = pk2bf(acc[cb][g * 4 + 2], acc[cb][g * 4 + 3]);
      }
    }
    asm volatile("s_waitcnt lgkmcnt(0)" ::: "memory");
    __builtin_amdgcn_sched_barrier(0);
#pragma unroll
    for (int i = 0; i < 4; ++i) {
      int flat = i * 1024 + lane * 16;
      int qr = flat >> 7, off = flat & 127;
      uint4 val = *(const uint4*)(eb + qr * 144 + off);
      *(uint4*)((char*)Opart + (gq0 + qr) * 512 + ch * 128 + off) = val;
    }
    asm volatile("s_waitcnt lgkmcnt(0)" ::: "memory");
    __builtin_amdgcn_sched_barrier(0);
  }
  if (lane < 32) {
    int q = q0w + l31;
    mpart[split * NSP + q] = m_r;
    lpart[split * NSP + q] = l_tot;
  }
}

// ---------------- K5: combine split partials -> attT bf16 [8192][256] -------
// 8 q-rows per block; each thread handles 8 channels via bf16x8 (vectorized).
__global__ __launch_bounds__(256) void k_combine(const ushort* __restrict__ Opart,
                                                 const float* __restrict__ mpart,
                                                 const float* __restrict__ lpart,
                                                 ushort* __restrict__ attT) {
  int q = blockIdx.x * 8 + (threadIdx.x >> 5);
  int c8 = threadIdx.x & 31;  // channels c8*8 .. c8*8+7
  float M = -1e30f;
#pragma unroll
  for (int s = 0; s < NSPLIT; ++s) M = fmaxf(M, mpart[s * NSP + q]);
  float L = 0.f;
  float av[8] = {};
#pragma unroll
  for (int s = 0; s < NSPLIT; ++s) {
    float ws = __builtin_amdgcn_exp2f(mpart[s * NSP + q] - M);
    L += ws * lpart[s * NSP + q];
    bf16x8 o = *(const bf16x8*)(Opart + ((size_t)s * NSP + q) * 256 + c8 * 8);
#pragma unroll
    for (int j = 0; j < 8; ++j) av[j] += ws * bf2f((ushort)o[j]);
  }
  float rL = 1.f / L;
  uint4 outv;
  outv.x = pk2bf(av[0] * rL, av[1] * rL);
  outv.y = pk2bf(av[2] * rL, av[3] * rL);
  outv.z = pk2bf(av[4] * rL, av[5] * rL);
  outv.w = pk2bf(av[6] * rL, av[7] * rL);
  *(uint4*)(attT + (size_t)q * 256 + c8 * 8) = outv;
}

// ---------------- K6: out = xn + ow @ att + ob ------------------------------
__global__ __launch_bounds__(256) void k_final(const ushort* __restrict__ attT, const ushort* __restrict__ wo,
                                               const float* __restrict__ ob, const float* __restrict__ x,
                                               const float* __restrict__ gw, const float* __restrict__ gb,
                                               const float* __restrict__ part, float* __restrict__ out) {
  __shared__ float sstat[2];
  int nb = blockIdx.x, obk = blockIdx.y;
  int w = threadIdx.x >> 6, lane = threadIdx.x & 63;
  int l16 = lane & 15, kgrp = lane >> 4;
  stat_finalize(part, threadIdx.x, sstat);
  int orow = obk * 64 + w * 16 + l16;
  bf16x8 a[8];
  const bf16x8* arow = (const bf16x8*)(wo + (size_t)orow * 256);
  for (int ks = 0; ks < 8; ++ks) a[ks] = arow[ks * 4 + kgrp];
  f32x4 acc[4];
  for (int ct = 0; ct < 4; ++ct) {
    int n = nb * 64 + ct * 16 + l16;
    const bf16x8* brow = (const bf16x8*)(attT + (size_t)n * 256);
    f32x4 c = {0.f, 0.f, 0.f, 0.f};
    for (int ks = 0; ks < 8; ++ks)
      c = __builtin_amdgcn_mfma_f32_16x16x32_bf16(a[ks], brow[ks * 4 + kgrp], c, 0, 0, 0);
    acc[ct] = c;
  }
  __syncthreads();
  float mean = sstat[0], rinv = sstat[1];
  for (int ct = 0; ct < 4; ++ct) {
    for (int r = 0; r < 4; ++r) {
      int o = obk * 64 + w * 16 + kgrp * 4 + r;
      int n = nb * 64 + ct * 16 + l16;
      float xv = x[(size_t)o * NSP + n];
      float xn = (xv - mean) * rinv * gw[o] + gb[o];
      out[(size_t)o * NSP + n] = xn + acc[ct][r] + ob[o];
    }
  }
}

extern "C" void kernel_launch(void* const* d_in, const int* in_sizes, int n_in,
                              void* d_out, int out_size, void* d_ws, size_t ws_size,
                              hipStream_t stream) {
  const float* x = (const float*)d_in[0];
  const float* gw = (const float*)d_in[1];
  const float* gb = (const float*)d_in[2];
  const float* qw = (const float*)d_in[3];
  const float* qbv = (const float*)d_in[4];
  const float* kw = (const float*)d_in[5];
  const float* kbv = (const float*)d_in[6];
  const float* vw = (const float*)d_in[7];
  const float* vbv = (const float*)d_in[8];
  const float* ow = (const float*)d_in[9];
  const float* obv = (const float*)d_in[10];
  float* out = (float*)d_out;
  char* ws = (char*)d_ws;
  const size_t KB = 1024, MB = 1048576;
  // region plan (high-water 49 MB):
  //  0..4K      part (live until k_final)
  //  64..448K   wqkv (dead after k_qkv) -> mpart (256K) overlays
  //  448..576K  wo (live until k_final)
  //  576..832K  lpart
  //  1..5MB     xnT (k_norm_t->k_qkv) -> attT (k_combine->k_final)
  //  5..9MB     qT
  //  9..13MB    k_tiles [256 tile][16KB]
  //  13..17MB   v_tiles [256 tile][16KB]
  //  17..49MB   Opart (8 splits, bf16)
  float* part = (float*)(ws);
  ushort* wqkv = (ushort*)(ws + 64 * KB);
  ushort* wo = (ushort*)(ws + 448 * KB);
  float* mpart = (float*)(ws + 64 * KB);    // overlays wqkv (dead by k_attn)
  float* lpart = (float*)(ws + 576 * KB);
  ushort* xnT = (ushort*)(ws + 1 * MB);
  ushort* qT = (ushort*)(ws + 5 * MB);
  ushort* k_tiles = (ushort*)(ws + 9 * MB);
  ushort* v_tiles = (ushort*)(ws + 13 * MB);
  ushort* Opart = (ushort*)(ws + 17 * MB);
  ushort* attT = xnT;  // alias: xnT dead after k_qkv

  k_pre<<<1536, 256, 0, stream>>>(x, part, qw, kw, vw, ow, wqkv, wo);
  k_norm_t<<<dim3(128, 4), 256, 0, stream>>>(x, gw, gb, part, xnT);
  k_qkv<<<dim3(128, 12), 256, 0, stream>>>(xnT, wqkv, qbv, kbv, vbv, qT, k_tiles, v_tiles);
  k_attn<<<256, 512, 0, stream>>>(qT, k_tiles, v_tiles, Opart, mpart, lpart);
  k_combine<<<NSP / 8, 256, 0, stream>>>(Opart, mpart, lpart, attT);
  k_final<<<dim3(128, 4), 256, 0, stream>>>(attT, wo, obv, x, gw, gb, part, out);
}